// Round 5
// baseline (332.818 us; speedup 1.0000x reference)
//
#include <hip/hip_runtime.h>

constexpr int T = 1024;
constexpr int B = 64;
constexpr int V = 512;
constexpr int L = 256;
constexpr int S = 2 * L + 1;   // 513

// ws layout:
// [0]      lse_rows : T*B floats (256 KB)
// [256K]   blankU   : T*B floats (256 KB)   exp(blank logit) per row
// [512K]   offsets  : B ints
// [1M]     packedU  : T*B*256 floats (64 MB) exp(label logits), blank-filled

// ---------------------------------------------------------------------------
// offsets[b] = exclusive prefix sum of label_lens (one wave, shfl scan)
// ---------------------------------------------------------------------------
__global__ __launch_bounds__(64) void offsets_kernel(
    const int* __restrict__ label_lens, int* __restrict__ offsets)
{
    int lane = threadIdx.x;
    int v = (lane < B) ? label_lens[lane] : 0;
    int x = v;
#pragma unroll
    for (int o = 1; o < 64; o <<= 1) {
        int y = __shfl_up(x, o, 64);
        if (lane >= o) x += y;
    }
    if (lane < B) offsets[lane] = x - v;
}

// ---------------------------------------------------------------------------
// Setup: one wave per (t,b) row. Computes exp of the whole row once:
//   lse_rows[r] = log(sum exp), packedU[r][j] = exp(logit of label j)
//   (blank-filled past lab_len), blankU[r] = exp(blank logit).
// No __syncthreads: each wave reads only LDS it wrote itself (lgkmcnt only).
// ---------------------------------------------------------------------------
__global__ __launch_bounds__(256) void setup_kernel(
    const float* __restrict__ acts, const int* __restrict__ labels,
    const int* __restrict__ label_lens, const int* __restrict__ offsets,
    float* __restrict__ lse_rows, float* __restrict__ packedU,
    float* __restrict__ blankU)
{
    __shared__ float rows[4][V];
    const int w    = threadIdx.x >> 6;
    const int lane = threadIdx.x & 63;
    const int r    = blockIdx.x * 4 + w;          // r = t*B + b
    const float* p = acts + (size_t)r * V;

    float4 x0 = ((const float4*)p)[lane];
    float4 x1 = ((const float4*)p)[lane + 64];
    float4 e0, e1;
    e0.x = __expf(x0.x); e0.y = __expf(x0.y); e0.z = __expf(x0.z); e0.w = __expf(x0.w);
    e1.x = __expf(x1.x); e1.y = __expf(x1.y); e1.z = __expf(x1.z); e1.w = __expf(x1.w);
    ((float4*)rows[w])[lane]      = e0;
    ((float4*)rows[w])[lane + 64] = e1;
    float s = e0.x + e0.y + e0.z + e0.w + e1.x + e1.y + e1.z + e1.w;
#pragma unroll
    for (int o = 32; o; o >>= 1) s += __shfl_xor(s, o, 64);
    if (lane == 0) lse_rows[r] = __logf(s);

    const int b       = r & (B - 1);
    const int lab_len = label_lens[b];
    const int off     = offsets[b];
    const float ub    = rows[w][0];
    const int j0 = 4 * lane;
    float q0 = (j0 + 0 < lab_len) ? rows[w][labels[min(off + j0 + 0, B * L - 1)]] : ub;
    float q1 = (j0 + 1 < lab_len) ? rows[w][labels[min(off + j0 + 1, B * L - 1)]] : ub;
    float q2 = (j0 + 2 < lab_len) ? rows[w][labels[min(off + j0 + 2, B * L - 1)]] : ub;
    float q3 = (j0 + 3 < lab_len) ? rows[w][labels[min(off + j0 + 3, B * L - 1)]] : ub;
    float4 gv = {q0, q1, q2, q3};
    ((float4*)(packedU + (size_t)r * 256))[lane] = gv;
    if (lane == 0) blankU[r] = ub;
}

// ---------------------------------------------------------------------------
// Fwd/bwd linear-space CTC scan on pre-exp'd packed values. Block b:
// wave0 = alpha fwd t=1..th, wave1 = beta bwd t=a_len-2..th+1 (+bracket W).
// Depth-8 prefetch pipeline in NAMED SCALARS (g0..g7,b0..b7) — R4's
// float[8][5]+lambda defeated SROA (VGPR_Count=44 → scratch), collapsing the
// pipeline. No transcendentals in the step (exps precomputed). Log-space
// junction (R3's linear dot flushed to 0 in fp32).
// ---------------------------------------------------------------------------
__global__ __launch_bounds__(128) void ctc_kernel(
    const int* __restrict__ labels, const int* __restrict__ act_lens,
    const int* __restrict__ label_lens, const int* __restrict__ offsets,
    const float* __restrict__ lse_rows, const float* __restrict__ packedU,
    const float* __restrict__ blankU, float* __restrict__ out)
{
    const int b    = blockIdx.x;
    const int wave = threadIdx.x >> 6;
    const int lane = threadIdx.x & 63;
    const int lab_len = label_lens[b];
    const int a_len   = act_lens[b];
    const int th      = (a_len - 1) >> 1;
    const int off     = offsets[b];

    // lane-owned labels (idx 4l..4l+3) + neighbors for allow flags
    int li0 = 4 * lane;
    int eprev = (li0 - 1 >= 0 && li0 - 1 < lab_len) ? labels[min(off + li0 - 1, B * L - 1)] : 0;
    int enext = (li0 + 4 < lab_len) ? labels[min(off + li0 + 4, B * L - 1)] : 0;
    int e0 = (li0 + 0 < lab_len) ? labels[min(off + li0 + 0, B * L - 1)] : 0;
    int e1 = (li0 + 1 < lab_len) ? labels[min(off + li0 + 1, B * L - 1)] : 0;
    int e2 = (li0 + 2 < lab_len) ? labels[min(off + li0 + 2, B * L - 1)] : 0;
    int e3 = (li0 + 3 < lab_len) ? labels[min(off + li0 + 3, B * L - 1)] : 0;

    const float aF0 = (8 * lane + 1 >= 2 && e0 != 0 && e0 != eprev) ? 1.f : 0.f;
    const float aF1 = (e1 != 0 && e1 != e0) ? 1.f : 0.f;
    const float aF2 = (e2 != 0 && e2 != e1) ? 1.f : 0.f;
    const float aF3 = (e3 != 0 && e3 != e2) ? 1.f : 0.f;
    const float aB0 = aF1;
    const float aB1 = aF2;
    const float aB2 = aF3;
    const float aB3 = (enext != 0 && enext != e3) ? 1.f : 0.f;

    __shared__ float sbr[S];
    __shared__ float s_accb;

    float A0 = 0.f, A1 = 0.f, A2 = 0.f, A3 = 0.f, A4 = 0.f,
          A5 = 0.f, A6 = 0.f, A7 = 0.f, A8 = 0.f;
    float acc = 0.f, sls = 0.f;
    float4 g0, g1, g2, g3, g4, g5, g6, g7;
    float  b0, b1, b2, b3, b4, b5, b6, b7;

#define LDROW(G, BL, RR) do {                                              \
        int rr_ = (RR);                                                    \
        G  = ((const float4*)packedU)[(size_t)rr_ * 64 + lane];            \
        BL = blankU[rr_];                                                  \
    } while (0)

#define RESCALE() do {                                                     \
        float m_ = fmaxf(A8, A0); m_ = fmaxf(m_, A1); m_ = fmaxf(m_, A2);  \
        m_ = fmaxf(m_, A3); m_ = fmaxf(m_, A4); m_ = fmaxf(m_, A5);        \
        m_ = fmaxf(m_, A6); m_ = fmaxf(m_, A7);                            \
        _Pragma("unroll")                                                  \
        for (int o_ = 32; o_; o_ >>= 1) m_ = fmaxf(m_, __shfl_xor(m_, o_, 64)); \
        m_ = fmaxf(m_, 1e-30f);                                            \
        float inv_ = __builtin_amdgcn_rcpf(m_);                            \
        acc += __logf(m_);                                                 \
        A0 *= inv_; A1 *= inv_; A2 *= inv_; A3 *= inv_; A4 *= inv_;        \
        A5 *= inv_; A6 *= inv_; A7 *= inv_; A8 *= inv_;                    \
    } while (0)

#define STEPF(G, BL) do {                                                  \
        float ub_ = (BL);                                                  \
        float pA7_ = __shfl_up(A7, 1, 64);                                 \
        if (lane == 0) pA7_ = 0.f;                                         \
        A8 = ub_  * (A8 + A7);                                             \
        A7 = G.w  * fmaf(aF3, A5, A7 + A6);                                \
        A6 = ub_  * (A6 + A5);                                             \
        A5 = G.z  * fmaf(aF2, A3, A5 + A4);                                \
        A4 = ub_  * (A4 + A3);                                             \
        A3 = G.y  * fmaf(aF1, A1, A3 + A2);                                \
        A2 = ub_  * (A2 + A1);                                             \
        A1 = G.x  * fmaf(aF0, pA7_, A1 + A0);                              \
        A0 = ub_  * (A0 + pA7_);                                           \
    } while (0)

#define STEPB(G, BL) do {                                                  \
        float ub_ = (BL);                                                  \
        float nB0_ = __shfl_down(A0, 1, 64);                               \
        float nB1_ = __shfl_down(A1, 1, 64);                               \
        if (lane == 63) { nB0_ = A8; nB1_ = 0.f; }                         \
        A8 = ub_  * A8;                                                    \
        A0 = ub_  * (A0 + A1);                                             \
        A1 = G.x  * fmaf(aB0, A3, A1 + A2);                                \
        A2 = ub_  * (A2 + A3);                                             \
        A3 = G.y  * fmaf(aB1, A5, A3 + A4);                                \
        A4 = ub_  * (A4 + A5);                                             \
        A5 = G.z  * fmaf(aB2, A7, A5 + A6);                                \
        A6 = ub_  * (A6 + A7);                                             \
        A7 = G.w  * fmaf(aB3, nB1_, A7 + nB0_);                            \
    } while (0)

    if (wave == 0) {
        // per-batch sum of row-lse (L2-resident)
        for (int t = lane; t < a_len; t += 64) sls += lse_rows[t * B + b];
#pragma unroll
        for (int o = 32; o; o >>= 1) sls += __shfl_xor(sls, o, 64);

        // alpha init (t = 0)
        if (lane == 0) {
            A0 = blankU[b];
            A1 = packedU[(size_t)b * 256];   // exp of label 0 (blank-filled)
        }

        LDROW(g0, b0, (1) * B + b); LDROW(g1, b1, (2) * B + b);
        LDROW(g2, b2, (3) * B + b); LDROW(g3, b3, (4) * B + b);
        LDROW(g4, b4, (5) * B + b); LDROW(g5, b5, (6) * B + b);
        LDROW(g6, b6, (7) * B + b); LDROW(g7, b7, (8) * B + b);

        int t = 1;
        while (t + 8 <= th + 1) {
            STEPF(g0, b0); LDROW(g0, b0, min(t +  8, T - 1) * B + b);
            STEPF(g1, b1); LDROW(g1, b1, min(t +  9, T - 1) * B + b);
            STEPF(g2, b2); LDROW(g2, b2, min(t + 10, T - 1) * B + b);
            STEPF(g3, b3); LDROW(g3, b3, min(t + 11, T - 1) * B + b);
            STEPF(g4, b4); LDROW(g4, b4, min(t + 12, T - 1) * B + b);
            STEPF(g5, b5); LDROW(g5, b5, min(t + 13, T - 1) * B + b);
            STEPF(g6, b6); LDROW(g6, b6, min(t + 14, T - 1) * B + b);
            STEPF(g7, b7); LDROW(g7, b7, min(t + 15, T - 1) * B + b);
            RESCALE();
            t += 8;
        }
        if (t + 0 <= th) STEPF(g0, b0);
        if (t + 1 <= th) STEPF(g1, b1);
        if (t + 2 <= th) STEPF(g2, b2);
        if (t + 3 <= th) STEPF(g3, b3);
        if (t + 4 <= th) STEPF(g4, b4);
        if (t + 5 <= th) STEPF(g5, b5);
        if (t + 6 <= th) STEPF(g6, b6);
        if (t + 7 <= th) STEPF(g7, b7);
        RESCALE();
    } else {
        // beta init (t = a_len-1)
        const int send = 2 * lab_len;
        {
            int rl = (a_len - 1) * B + b;
            float ubl = blankU[rl];
            float ue  = (lab_len > 0) ? packedU[(size_t)rl * 256 + (lab_len - 1)] : 0.f;
            int s0 = 8 * lane;
            A0 = (s0 + 0 == send) ? ubl : ((s0 + 0 == send - 1) ? ue : 0.f);
            A1 = (s0 + 1 == send) ? ubl : ((s0 + 1 == send - 1) ? ue : 0.f);
            A2 = (s0 + 2 == send) ? ubl : ((s0 + 2 == send - 1) ? ue : 0.f);
            A3 = (s0 + 3 == send) ? ubl : ((s0 + 3 == send - 1) ? ue : 0.f);
            A4 = (s0 + 4 == send) ? ubl : ((s0 + 4 == send - 1) ? ue : 0.f);
            A5 = (s0 + 5 == send) ? ubl : ((s0 + 5 == send - 1) ? ue : 0.f);
            A6 = (s0 + 6 == send) ? ubl : ((s0 + 6 == send - 1) ? ue : 0.f);
            A7 = (s0 + 7 == send) ? ubl : ((s0 + 7 == send - 1) ? ue : 0.f);
            A8 = (lane == 63 && send == 512) ? ubl : 0.f;
        }

        LDROW(g0, b0, max(a_len - 2, 0) * B + b);
        LDROW(g1, b1, max(a_len - 3, 0) * B + b);
        LDROW(g2, b2, max(a_len - 4, 0) * B + b);
        LDROW(g3, b3, max(a_len - 5, 0) * B + b);
        LDROW(g4, b4, max(a_len - 6, 0) * B + b);
        LDROW(g5, b5, max(a_len - 7, 0) * B + b);
        LDROW(g6, b6, max(a_len - 8, 0) * B + b);
        LDROW(g7, b7, max(a_len - 9, 0) * B + b);

        int t = a_len - 2;
        while (t - 8 >= th) {
            STEPB(g0, b0); LDROW(g0, b0, max(t -  8, 0) * B + b);
            STEPB(g1, b1); LDROW(g1, b1, max(t -  9, 0) * B + b);
            STEPB(g2, b2); LDROW(g2, b2, max(t - 10, 0) * B + b);
            STEPB(g3, b3); LDROW(g3, b3, max(t - 11, 0) * B + b);
            STEPB(g4, b4); LDROW(g4, b4, max(t - 12, 0) * B + b);
            STEPB(g5, b5); LDROW(g5, b5, max(t - 13, 0) * B + b);
            STEPB(g6, b6); LDROW(g6, b6, max(t - 14, 0) * B + b);
            STEPB(g7, b7); LDROW(g7, b7, max(t - 15, 0) * B + b);
            RESCALE();
            t -= 8;
        }
        if (t - 0 >= th + 1) STEPB(g0, b0);
        if (t - 1 >= th + 1) STEPB(g1, b1);
        if (t - 2 >= th + 1) STEPB(g2, b2);
        if (t - 3 >= th + 1) STEPB(g3, b3);
        if (t - 4 >= th + 1) STEPB(g4, b4);
        if (t - 5 >= th + 1) STEPB(g5, b5);
        if (t - 6 >= th + 1) STEPB(g6, b6);
        if (t - 7 >= th + 1) STEPB(g7, b7);
        RESCALE();

        // bracket W(s) = B(s) + B(s+1) + allowB*B(s+2), B = beta_{th+1}
        {
            float nB0 = __shfl_down(A0, 1, 64);
            float nB1 = __shfl_down(A1, 1, 64);
            if (lane == 63) { nB0 = A8; nB1 = 0.f; }
            float w0 = A0 + A1;
            float w1 = fmaf(aB0, A3, A1 + A2);
            float w2 = A2 + A3;
            float w3 = fmaf(aB1, A5, A3 + A4);
            float w4 = A4 + A5;
            float w5 = fmaf(aB2, A7, A5 + A6);
            float w6 = A6 + A7;
            float w7 = fmaf(aB3, nB1, A7 + nB0);
            int s0 = 8 * lane;
            sbr[s0 + 0] = w0; sbr[s0 + 1] = w1; sbr[s0 + 2] = w2; sbr[s0 + 3] = w3;
            sbr[s0 + 4] = w4; sbr[s0 + 5] = w5; sbr[s0 + 6] = w6; sbr[s0 + 7] = w7;
            if (lane == 63) sbr[512] = A8;
            if (lane == 0)  s_accb = acc;
        }
    }
    __syncthreads();
    if (wave == 0) {
        // LOG-space junction (linear dot underflows fp32 — R3's inf)
        int s0 = 8 * lane;
        float p0 = __logf(fmaxf(A0, 1e-37f)) + __logf(fmaxf(sbr[s0 + 0], 1e-37f));
        float p1 = __logf(fmaxf(A1, 1e-37f)) + __logf(fmaxf(sbr[s0 + 1], 1e-37f));
        float p2 = __logf(fmaxf(A2, 1e-37f)) + __logf(fmaxf(sbr[s0 + 2], 1e-37f));
        float p3 = __logf(fmaxf(A3, 1e-37f)) + __logf(fmaxf(sbr[s0 + 3], 1e-37f));
        float p4 = __logf(fmaxf(A4, 1e-37f)) + __logf(fmaxf(sbr[s0 + 4], 1e-37f));
        float p5 = __logf(fmaxf(A5, 1e-37f)) + __logf(fmaxf(sbr[s0 + 5], 1e-37f));
        float p6 = __logf(fmaxf(A6, 1e-37f)) + __logf(fmaxf(sbr[s0 + 6], 1e-37f));
        float p7 = __logf(fmaxf(A7, 1e-37f)) + __logf(fmaxf(sbr[s0 + 7], 1e-37f));
        float p8 = -3.0e38f;
        if (lane == 63) p8 = __logf(fmaxf(A8, 1e-37f)) + __logf(fmaxf(sbr[512], 1e-37f));
        float pmax = fmaxf(fmaxf(fmaxf(p0, p1), fmaxf(p2, p3)),
                           fmaxf(fmaxf(p4, p5), fmaxf(p6, p7)));
        pmax = fmaxf(pmax, p8);
#pragma unroll
        for (int o = 32; o; o >>= 1) pmax = fmaxf(pmax, __shfl_xor(pmax, o, 64));
        float dot = __expf(p0 - pmax) + __expf(p1 - pmax) + __expf(p2 - pmax)
                  + __expf(p3 - pmax) + __expf(p4 - pmax) + __expf(p5 - pmax)
                  + __expf(p6 - pmax) + __expf(p7 - pmax);
        if (lane == 63) dot += __expf(p8 - pmax);
#pragma unroll
        for (int o = 32; o; o >>= 1) dot += __shfl_xor(dot, o, 64);
        if (lane == 0) {
            float loss = sls - acc - s_accb - (pmax + __logf(dot));
            atomicAdd(out, loss);
        }
    }
#undef LDROW
#undef RESCALE
#undef STEPF
#undef STEPB
}

extern "C" void kernel_launch(void* const* d_in, const int* in_sizes, int n_in,
                              void* d_out, int out_size, void* d_ws, size_t ws_size,
                              hipStream_t stream) {
    const float* acts       = (const float*)d_in[0];
    const int*   labels     = (const int*)d_in[1];
    const int*   act_lens   = (const int*)d_in[2];
    const int*   label_lens = (const int*)d_in[3];
    float*       out        = (float*)d_out;

    float* lse_rows = (float*)d_ws;
    float* blankU   = (float*)((char*)d_ws + (size_t)T * B * 4);
    int*   offsets  = (int*)  ((char*)d_ws + (size_t)2 * T * B * 4);
    float* packedU  = (float*)((char*)d_ws + (1u << 20));

    hipMemsetAsync(d_out, 0, sizeof(float), stream);

    offsets_kernel<<<1, 64, 0, stream>>>(label_lens, offsets);
    setup_kernel<<<T * B / 4, 256, 0, stream>>>(
        acts, labels, label_lens, offsets, lse_rows, packedU, blankU);
    ctc_kernel<<<B, 128, 0, stream>>>(
        labels, act_lens, label_lens, offsets, lse_rows, packedU, blankU, out);
}

// Round 6
// 319.105 us; speedup vs baseline: 1.0430x; 1.0430x over previous
//
#include <hip/hip_runtime.h>

constexpr int T = 1024;
constexpr int B = 64;
constexpr int V = 512;
constexpr int L = 256;
constexpr int S = 2 * L + 1;   // 513

typedef float f32x4 __attribute__((ext_vector_type(4)));

__device__ __forceinline__ float bf2f(unsigned short h) {
    return __uint_as_float(((unsigned)h) << 16);
}
__device__ __forceinline__ unsigned short f2bf(float f) {  // RNE
    unsigned u = __float_as_uint(f);
    u += 0x7fffu + ((u >> 16) & 1u);
    return (unsigned short)(u >> 16);
}

// ws layout:
// [0]      lse_rows : T*B floats (256 KB)
// [256K]   blankU   : T*B floats (256 KB)   exp(blank logit) per row
// [512K]   offsets  : B ints
// [1M]     packedU  : T*B*256 bf16 (32 MB)  exp(label logits), blank-filled

__global__ __launch_bounds__(64) void offsets_kernel(
    const int* __restrict__ label_lens, int* __restrict__ offsets)
{
    int lane = threadIdx.x;
    int v = (lane < B) ? label_lens[lane] : 0;
    int x = v;
#pragma unroll
    for (int o = 1; o < 64; o <<= 1) {
        int y = __shfl_up(x, o, 64);
        if (lane >= o) x += y;
    }
    if (lane < B) offsets[lane] = x - v;
}

// ---------------------------------------------------------------------------
// Setup: one wave per (t,b) row. exp the row once; emit row-lse + bf16-packed
// exp(label logits) (+blank). acts read with NONTEMPORAL loads (read exactly
// once ever — keep them from evicting packedU out of L3 before the scan).
// ---------------------------------------------------------------------------
__global__ __launch_bounds__(256) void setup_kernel(
    const float* __restrict__ acts, const int* __restrict__ labels,
    const int* __restrict__ label_lens, const int* __restrict__ offsets,
    float* __restrict__ lse_rows, unsigned short* __restrict__ packedU,
    float* __restrict__ blankU)
{
    __shared__ float rows[4][V];
    const int w    = threadIdx.x >> 6;
    const int lane = threadIdx.x & 63;
    const int r    = blockIdx.x * 4 + w;          // r = t*B + b
    const f32x4* p = (const f32x4*)(acts + (size_t)r * V);

    f32x4 x0 = __builtin_nontemporal_load(p + lane);
    f32x4 x1 = __builtin_nontemporal_load(p + lane + 64);
    f32x4 e0, e1;
    e0.x = __expf(x0.x); e0.y = __expf(x0.y); e0.z = __expf(x0.z); e0.w = __expf(x0.w);
    e1.x = __expf(x1.x); e1.y = __expf(x1.y); e1.z = __expf(x1.z); e1.w = __expf(x1.w);
    ((f32x4*)rows[w])[lane]      = e0;
    ((f32x4*)rows[w])[lane + 64] = e1;
    float s = e0.x + e0.y + e0.z + e0.w + e1.x + e1.y + e1.z + e1.w;
#pragma unroll
    for (int o = 32; o; o >>= 1) s += __shfl_xor(s, o, 64);
    if (lane == 0) lse_rows[r] = __logf(s);

    const int b       = r & (B - 1);
    const int lab_len = label_lens[b];
    const int off     = offsets[b];
    const float ub    = rows[w][0];
    const int j0 = 4 * lane;
    float q0 = (j0 + 0 < lab_len) ? rows[w][labels[min(off + j0 + 0, B * L - 1)]] : ub;
    float q1 = (j0 + 1 < lab_len) ? rows[w][labels[min(off + j0 + 1, B * L - 1)]] : ub;
    float q2 = (j0 + 2 < lab_len) ? rows[w][labels[min(off + j0 + 2, B * L - 1)]] : ub;
    float q3 = (j0 + 3 < lab_len) ? rows[w][labels[min(off + j0 + 3, B * L - 1)]] : ub;
    ushort4 hv = {f2bf(q0), f2bf(q1), f2bf(q2), f2bf(q3)};
    ((ushort4*)packedU)[(size_t)r * 64 + lane] = hv;
    if (lane == 0) blankU[r] = ub;
}

// ---------------------------------------------------------------------------
// Fwd/bwd linear-space CTC scan on bf16 pre-exp'd packed rows. Block b:
// wave0 = alpha fwd t=1..th, wave1 = beta bwd t=a_len-2..th+1 (+bracket W).
// __launch_bounds__(128,1): R4/R5's VGPR_Count=44/48 proved the allocator
// collapsed the depth-8 pipeline (134.7us twice, identical degenerate
// schedule); occupancy is irrelevant here (64 blocks / 256 CUs), so open the
// VGPR budget and keep 8 rows of loads in flight. Slot = ushort4+float
// (3 VGPRs). Log-space junction (linear dot underflows fp32).
// ---------------------------------------------------------------------------
__global__ __launch_bounds__(128, 1) void ctc_kernel(
    const int* __restrict__ labels, const int* __restrict__ act_lens,
    const int* __restrict__ label_lens, const int* __restrict__ offsets,
    const float* __restrict__ lse_rows, const unsigned short* __restrict__ packedU,
    const float* __restrict__ blankU, float* __restrict__ out)
{
    const int b    = blockIdx.x;
    const int wave = threadIdx.x >> 6;
    const int lane = threadIdx.x & 63;
    const int lab_len = label_lens[b];
    const int a_len   = act_lens[b];
    const int th      = (a_len - 1) >> 1;
    const int off     = offsets[b];

    int li0 = 4 * lane;
    int eprev = (li0 - 1 >= 0 && li0 - 1 < lab_len) ? labels[min(off + li0 - 1, B * L - 1)] : 0;
    int enext = (li0 + 4 < lab_len) ? labels[min(off + li0 + 4, B * L - 1)] : 0;
    int e0 = (li0 + 0 < lab_len) ? labels[min(off + li0 + 0, B * L - 1)] : 0;
    int e1 = (li0 + 1 < lab_len) ? labels[min(off + li0 + 1, B * L - 1)] : 0;
    int e2 = (li0 + 2 < lab_len) ? labels[min(off + li0 + 2, B * L - 1)] : 0;
    int e3 = (li0 + 3 < lab_len) ? labels[min(off + li0 + 3, B * L - 1)] : 0;

    const float aF0 = (8 * lane + 1 >= 2 && e0 != 0 && e0 != eprev) ? 1.f : 0.f;
    const float aF1 = (e1 != 0 && e1 != e0) ? 1.f : 0.f;
    const float aF2 = (e2 != 0 && e2 != e1) ? 1.f : 0.f;
    const float aF3 = (e3 != 0 && e3 != e2) ? 1.f : 0.f;
    const float aB0 = aF1, aB1 = aF2, aB2 = aF3;
    const float aB3 = (enext != 0 && enext != e3) ? 1.f : 0.f;

    __shared__ float sbr[S];
    __shared__ float s_accb;

    float A0 = 0.f, A1 = 0.f, A2 = 0.f, A3 = 0.f, A4 = 0.f,
          A5 = 0.f, A6 = 0.f, A7 = 0.f, A8 = 0.f;
    float acc = 0.f, sls = 0.f;
    ushort4 h0, h1, h2, h3, h4, h5, h6, h7;
    float   b0, b1, b2, b3, b4, b5, b6, b7;

#define LDROW(H, BL, RR) do {                                              \
        int rr_ = (RR);                                                    \
        H  = ((const ushort4*)packedU)[(size_t)rr_ * 64 + lane];           \
        BL = blankU[rr_];                                                  \
    } while (0)

#define RESCALE() do {                                                     \
        float m_ = fmaxf(A8, A0); m_ = fmaxf(m_, A1); m_ = fmaxf(m_, A2);  \
        m_ = fmaxf(m_, A3); m_ = fmaxf(m_, A4); m_ = fmaxf(m_, A5);        \
        m_ = fmaxf(m_, A6); m_ = fmaxf(m_, A7);                            \
        _Pragma("unroll")                                                  \
        for (int o_ = 32; o_; o_ >>= 1) m_ = fmaxf(m_, __shfl_xor(m_, o_, 64)); \
        m_ = fmaxf(m_, 1e-30f);                                            \
        float inv_ = __builtin_amdgcn_rcpf(m_);                            \
        acc += __logf(m_);                                                 \
        A0 *= inv_; A1 *= inv_; A2 *= inv_; A3 *= inv_; A4 *= inv_;        \
        A5 *= inv_; A6 *= inv_; A7 *= inv_; A8 *= inv_;                    \
    } while (0)

#define STEPF(H, BL) do {                                                  \
        float ub_ = (BL);                                                  \
        float u0_ = bf2f(H.x), u1_ = bf2f(H.y);                            \
        float u2_ = bf2f(H.z), u3_ = bf2f(H.w);                            \
        float pA7_ = __shfl_up(A7, 1, 64);                                 \
        if (lane == 0) pA7_ = 0.f;                                         \
        A8 = ub_ * (A8 + A7);                                              \
        A7 = u3_ * fmaf(aF3, A5, A7 + A6);                                 \
        A6 = ub_ * (A6 + A5);                                              \
        A5 = u2_ * fmaf(aF2, A3, A5 + A4);                                 \
        A4 = ub_ * (A4 + A3);                                              \
        A3 = u1_ * fmaf(aF1, A1, A3 + A2);                                 \
        A2 = ub_ * (A2 + A1);                                              \
        A1 = u0_ * fmaf(aF0, pA7_, A1 + A0);                               \
        A0 = ub_ * (A0 + pA7_);                                            \
    } while (0)

#define STEPB(H, BL) do {                                                  \
        float ub_ = (BL);                                                  \
        float u0_ = bf2f(H.x), u1_ = bf2f(H.y);                            \
        float u2_ = bf2f(H.z), u3_ = bf2f(H.w);                            \
        float nB0_ = __shfl_down(A0, 1, 64);                               \
        float nB1_ = __shfl_down(A1, 1, 64);                               \
        if (lane == 63) { nB0_ = A8; nB1_ = 0.f; }                         \
        A8 = ub_ * A8;                                                     \
        A0 = ub_ * (A0 + A1);                                              \
        A1 = u0_ * fmaf(aB0, A3, A1 + A2);                                 \
        A2 = ub_ * (A2 + A3);                                              \
        A3 = u1_ * fmaf(aB1, A5, A3 + A4);                                 \
        A4 = ub_ * (A4 + A5);                                              \
        A5 = u2_ * fmaf(aB2, A7, A5 + A6);                                 \
        A6 = ub_ * (A6 + A7);                                              \
        A7 = u3_ * fmaf(aB3, nB1_, A7 + nB0_);                             \
    } while (0)

    if (wave == 0) {
        for (int t = lane; t < a_len; t += 64) sls += lse_rows[t * B + b];
#pragma unroll
        for (int o = 32; o; o >>= 1) sls += __shfl_xor(sls, o, 64);

        if (lane == 0) {
            A0 = blankU[b];
            A1 = bf2f(packedU[(size_t)b * 256]);
        }

        LDROW(h0, b0, (1) * B + b); LDROW(h1, b1, (2) * B + b);
        LDROW(h2, b2, (3) * B + b); LDROW(h3, b3, (4) * B + b);
        LDROW(h4, b4, (5) * B + b); LDROW(h5, b5, (6) * B + b);
        LDROW(h6, b6, (7) * B + b); LDROW(h7, b7, (8) * B + b);

        int t = 1;
        while (t + 8 <= th + 1) {
            STEPF(h0, b0); LDROW(h0, b0, min(t +  8, T - 1) * B + b);
            STEPF(h1, b1); LDROW(h1, b1, min(t +  9, T - 1) * B + b);
            STEPF(h2, b2); LDROW(h2, b2, min(t + 10, T - 1) * B + b);
            STEPF(h3, b3); LDROW(h3, b3, min(t + 11, T - 1) * B + b);
            STEPF(h4, b4); LDROW(h4, b4, min(t + 12, T - 1) * B + b);
            STEPF(h5, b5); LDROW(h5, b5, min(t + 13, T - 1) * B + b);
            STEPF(h6, b6); LDROW(h6, b6, min(t + 14, T - 1) * B + b);
            STEPF(h7, b7); LDROW(h7, b7, min(t + 15, T - 1) * B + b);
            RESCALE();
            t += 8;
        }
        if (t + 0 <= th) STEPF(h0, b0);
        if (t + 1 <= th) STEPF(h1, b1);
        if (t + 2 <= th) STEPF(h2, b2);
        if (t + 3 <= th) STEPF(h3, b3);
        if (t + 4 <= th) STEPF(h4, b4);
        if (t + 5 <= th) STEPF(h5, b5);
        if (t + 6 <= th) STEPF(h6, b6);
        if (t + 7 <= th) STEPF(h7, b7);
        RESCALE();
    } else {
        const int send = 2 * lab_len;
        {
            int rl = (a_len - 1) * B + b;
            float ubl = blankU[rl];
            float ue  = (lab_len > 0) ? bf2f(packedU[(size_t)rl * 256 + (lab_len - 1)]) : 0.f;
            int s0 = 8 * lane;
            A0 = (s0 + 0 == send) ? ubl : ((s0 + 0 == send - 1) ? ue : 0.f);
            A1 = (s0 + 1 == send) ? ubl : ((s0 + 1 == send - 1) ? ue : 0.f);
            A2 = (s0 + 2 == send) ? ubl : ((s0 + 2 == send - 1) ? ue : 0.f);
            A3 = (s0 + 3 == send) ? ubl : ((s0 + 3 == send - 1) ? ue : 0.f);
            A4 = (s0 + 4 == send) ? ubl : ((s0 + 4 == send - 1) ? ue : 0.f);
            A5 = (s0 + 5 == send) ? ubl : ((s0 + 5 == send - 1) ? ue : 0.f);
            A6 = (s0 + 6 == send) ? ubl : ((s0 + 6 == send - 1) ? ue : 0.f);
            A7 = (s0 + 7 == send) ? ubl : ((s0 + 7 == send - 1) ? ue : 0.f);
            A8 = (lane == 63 && send == 512) ? ubl : 0.f;
        }

        LDROW(h0, b0, max(a_len - 2, 0) * B + b);
        LDROW(h1, b1, max(a_len - 3, 0) * B + b);
        LDROW(h2, b2, max(a_len - 4, 0) * B + b);
        LDROW(h3, b3, max(a_len - 5, 0) * B + b);
        LDROW(h4, b4, max(a_len - 6, 0) * B + b);
        LDROW(h5, b5, max(a_len - 7, 0) * B + b);
        LDROW(h6, b6, max(a_len - 8, 0) * B + b);
        LDROW(h7, b7, max(a_len - 9, 0) * B + b);

        int t = a_len - 2;
        while (t - 8 >= th) {
            STEPB(h0, b0); LDROW(h0, b0, max(t -  8, 0) * B + b);
            STEPB(h1, b1); LDROW(h1, b1, max(t -  9, 0) * B + b);
            STEPB(h2, b2); LDROW(h2, b2, max(t - 10, 0) * B + b);
            STEPB(h3, b3); LDROW(h3, b3, max(t - 11, 0) * B + b);
            STEPB(h4, b4); LDROW(h4, b4, max(t - 12, 0) * B + b);
            STEPB(h5, b5); LDROW(h5, b5, max(t - 13, 0) * B + b);
            STEPB(h6, b6); LDROW(h6, b6, max(t - 14, 0) * B + b);
            STEPB(h7, b7); LDROW(h7, b7, max(t - 15, 0) * B + b);
            RESCALE();
            t -= 8;
        }
        if (t - 0 >= th + 1) STEPB(h0, b0);
        if (t - 1 >= th + 1) STEPB(h1, b1);
        if (t - 2 >= th + 1) STEPB(h2, b2);
        if (t - 3 >= th + 1) STEPB(h3, b3);
        if (t - 4 >= th + 1) STEPB(h4, b4);
        if (t - 5 >= th + 1) STEPB(h5, b5);
        if (t - 6 >= th + 1) STEPB(h6, b6);
        if (t - 7 >= th + 1) STEPB(h7, b7);
        RESCALE();

        {
            float nB0 = __shfl_down(A0, 1, 64);
            float nB1 = __shfl_down(A1, 1, 64);
            if (lane == 63) { nB0 = A8; nB1 = 0.f; }
            float w0 = A0 + A1;
            float w1 = fmaf(aB0, A3, A1 + A2);
            float w2 = A2 + A3;
            float w3 = fmaf(aB1, A5, A3 + A4);
            float w4 = A4 + A5;
            float w5 = fmaf(aB2, A7, A5 + A6);
            float w6 = A6 + A7;
            float w7 = fmaf(aB3, nB1, A7 + nB0);
            int s0 = 8 * lane;
            sbr[s0 + 0] = w0; sbr[s0 + 1] = w1; sbr[s0 + 2] = w2; sbr[s0 + 3] = w3;
            sbr[s0 + 4] = w4; sbr[s0 + 5] = w5; sbr[s0 + 6] = w6; sbr[s0 + 7] = w7;
            if (lane == 63) sbr[512] = A8;
            if (lane == 0)  s_accb = acc;
        }
    }
    __syncthreads();
    if (wave == 0) {
        int s0 = 8 * lane;
        float p0 = __logf(fmaxf(A0, 1e-37f)) + __logf(fmaxf(sbr[s0 + 0], 1e-37f));
        float p1 = __logf(fmaxf(A1, 1e-37f)) + __logf(fmaxf(sbr[s0 + 1], 1e-37f));
        float p2 = __logf(fmaxf(A2, 1e-37f)) + __logf(fmaxf(sbr[s0 + 2], 1e-37f));
        float p3 = __logf(fmaxf(A3, 1e-37f)) + __logf(fmaxf(sbr[s0 + 3], 1e-37f));
        float p4 = __logf(fmaxf(A4, 1e-37f)) + __logf(fmaxf(sbr[s0 + 4], 1e-37f));
        float p5 = __logf(fmaxf(A5, 1e-37f)) + __logf(fmaxf(sbr[s0 + 5], 1e-37f));
        float p6 = __logf(fmaxf(A6, 1e-37f)) + __logf(fmaxf(sbr[s0 + 6], 1e-37f));
        float p7 = __logf(fmaxf(A7, 1e-37f)) + __logf(fmaxf(sbr[s0 + 7], 1e-37f));
        float p8 = -3.0e38f;
        if (lane == 63) p8 = __logf(fmaxf(A8, 1e-37f)) + __logf(fmaxf(sbr[512], 1e-37f));
        float pmax = fmaxf(fmaxf(fmaxf(p0, p1), fmaxf(p2, p3)),
                           fmaxf(fmaxf(p4, p5), fmaxf(p6, p7)));
        pmax = fmaxf(pmax, p8);
#pragma unroll
        for (int o = 32; o; o >>= 1) pmax = fmaxf(pmax, __shfl_xor(pmax, o, 64));
        float dot = __expf(p0 - pmax) + __expf(p1 - pmax) + __expf(p2 - pmax)
                  + __expf(p3 - pmax) + __expf(p4 - pmax) + __expf(p5 - pmax)
                  + __expf(p6 - pmax) + __expf(p7 - pmax);
        if (lane == 63) dot += __expf(p8 - pmax);
#pragma unroll
        for (int o = 32; o; o >>= 1) dot += __shfl_xor(dot, o, 64);
        if (lane == 0) {
            float loss = sls - acc - s_accb - (pmax + __logf(dot));
            atomicAdd(out, loss);
        }
    }
#undef LDROW
#undef RESCALE
#undef STEPF
#undef STEPB
}

extern "C" void kernel_launch(void* const* d_in, const int* in_sizes, int n_in,
                              void* d_out, int out_size, void* d_ws, size_t ws_size,
                              hipStream_t stream) {
    const float* acts       = (const float*)d_in[0];
    const int*   labels     = (const int*)d_in[1];
    const int*   act_lens   = (const int*)d_in[2];
    const int*   label_lens = (const int*)d_in[3];
    float*       out        = (float*)d_out;

    float*          lse_rows = (float*)d_ws;
    float*          blankU   = (float*)((char*)d_ws + (size_t)T * B * 4);
    int*            offsets  = (int*)  ((char*)d_ws + (size_t)2 * T * B * 4);
    unsigned short* packedU  = (unsigned short*)((char*)d_ws + (1u << 20));

    hipMemsetAsync(d_out, 0, sizeof(float), stream);

    offsets_kernel<<<1, 64, 0, stream>>>(label_lens, offsets);
    setup_kernel<<<T * B / 4, 256, 0, stream>>>(
        acts, labels, label_lens, offsets, lse_rows, packedU, blankU);
    ctc_kernel<<<B, 128, 0, stream>>>(
        labels, act_lens, label_lens, offsets, lse_rows, packedU, blankU, out);
}

// Round 7
// 279.448 us; speedup vs baseline: 1.1910x; 1.1419x over previous
//
#include <hip/hip_runtime.h>

constexpr int T = 1024;
constexpr int B = 64;
constexpr int V = 512;
constexpr int L = 256;
constexpr int S = 2 * L + 1;   // 513
constexpr int C = 16;          // scan chunk rows (8 KB staged per chunk)

typedef float f32x4 __attribute__((ext_vector_type(4)));

__device__ __forceinline__ unsigned short f2bf(float f) {  // RNE
    unsigned u = __float_as_uint(f);
    u += 0x7fffu + ((u >> 16) & 1u);
    return (unsigned short)(u >> 16);
}

// ws layout (batch-major now):
// [0]      lse_rows : B*T floats (256 KB)   [b*T+t]
// [256K]   blankU   : B*T floats (256 KB)   [b*T+t]  exp(blank logit)
// [512K]   offsets  : B ints
// [1M]     packedU  : B*T*256 bf16 (32 MB)  [(b*T+t)*256+j] exp(label logits)

__global__ __launch_bounds__(64) void offsets_kernel(
    const int* __restrict__ label_lens, int* __restrict__ offsets)
{
    int lane = threadIdx.x;
    int v = (lane < B) ? label_lens[lane] : 0;
    int x = v;
#pragma unroll
    for (int o = 1; o < 64; o <<= 1) {
        int y = __shfl_up(x, o, 64);
        if (lane >= o) x += y;
    }
    if (lane < B) offsets[lane] = x - v;
}

// ---------------------------------------------------------------------------
// Setup: one wave per TWO (t,b) rows (4 dwordx4 issued upfront for MLP).
// exp the rows once; emit row-lse + bf16 exp(label logits) + blank, all in
// BATCH-MAJOR layout so the scan's chunks are contiguous.
// ---------------------------------------------------------------------------
__global__ __launch_bounds__(256) void setup_kernel(
    const float* __restrict__ acts, const int* __restrict__ labels,
    const int* __restrict__ label_lens, const int* __restrict__ offsets,
    float* __restrict__ lse_rows, unsigned short* __restrict__ packedU,
    float* __restrict__ blankU)
{
    __shared__ float rows[4][2][V];          // 16 KB
    const int w    = threadIdx.x >> 6;
    const int lane = threadIdx.x & 63;
    const int rbase = (blockIdx.x * 4 + w) * 2;     // rows rbase, rbase+1
    const f32x4* p = (const f32x4*)(acts + (size_t)rbase * V);

    f32x4 xa0 = __builtin_nontemporal_load(p + lane);
    f32x4 xa1 = __builtin_nontemporal_load(p + lane + 64);
    f32x4 xb0 = __builtin_nontemporal_load(p + lane + 128);
    f32x4 xb1 = __builtin_nontemporal_load(p + lane + 192);
    f32x4 ea0, ea1, eb0, eb1;
    ea0.x=__expf(xa0.x); ea0.y=__expf(xa0.y); ea0.z=__expf(xa0.z); ea0.w=__expf(xa0.w);
    ea1.x=__expf(xa1.x); ea1.y=__expf(xa1.y); ea1.z=__expf(xa1.z); ea1.w=__expf(xa1.w);
    eb0.x=__expf(xb0.x); eb0.y=__expf(xb0.y); eb0.z=__expf(xb0.z); eb0.w=__expf(xb0.w);
    eb1.x=__expf(xb1.x); eb1.y=__expf(xb1.y); eb1.z=__expf(xb1.z); eb1.w=__expf(xb1.w);
    ((f32x4*)rows[w][0])[lane]      = ea0;
    ((f32x4*)rows[w][0])[lane + 64] = ea1;
    ((f32x4*)rows[w][1])[lane]      = eb0;
    ((f32x4*)rows[w][1])[lane + 64] = eb1;
    float sa = ea0.x+ea0.y+ea0.z+ea0.w + ea1.x+ea1.y+ea1.z+ea1.w;
    float sb = eb0.x+eb0.y+eb0.z+eb0.w + eb1.x+eb1.y+eb1.z+eb1.w;
#pragma unroll
    for (int o = 32; o; o >>= 1) { sa += __shfl_xor(sa, o, 64); sb += __shfl_xor(sb, o, 64); }

#pragma unroll
    for (int rr = 0; rr < 2; ++rr) {
        const int r = rbase + rr;
        const int b = r & (B - 1), t = r >> 6;    // r = t*B + b
        const float* rw = rows[w][rr];
        const int lab_len = label_lens[b];
        const int off     = offsets[b];
        const float ubk   = rw[0];
        const int j0 = 4 * lane;
        float q0 = (j0 + 0 < lab_len) ? rw[labels[min(off + j0 + 0, B * L - 1)]] : ubk;
        float q1 = (j0 + 1 < lab_len) ? rw[labels[min(off + j0 + 1, B * L - 1)]] : ubk;
        float q2 = (j0 + 2 < lab_len) ? rw[labels[min(off + j0 + 2, B * L - 1)]] : ubk;
        float q3 = (j0 + 3 < lab_len) ? rw[labels[min(off + j0 + 3, B * L - 1)]] : ubk;
        ushort4 hv = {f2bf(q0), f2bf(q1), f2bf(q2), f2bf(q3)};
        ((ushort4*)packedU)[(size_t)(b * T + t) * 64 + lane] = hv;
        if (lane == 0) {
            lse_rows[b * T + t] = __logf(rr ? sb : sa);
            blankU[b * T + t]   = ubk;
        }
    }
}

// ---------------------------------------------------------------------------
// Fwd/bwd linear-space CTC scan, chunked LDS double-buffer. R4-R6 proved the
// scheduler will not pipeline per-step scattered global loads (VGPR stuck at
// 44, ~575 cyc/step = 1 HBM latency). Here the global reads are BULK
// (8 dwordx4/lane, contiguous 8 KB chunk, batch-major layout) into registers,
// ds_write'd to a double buffer; the serial steps read LDS only (~120 cyc,
// covered by the unrolled 16-step body). vmcnt waits land at the ds_write,
// one full chunk (~1000 cyc) after issue. No barriers in the loops.
// ---------------------------------------------------------------------------
__global__ __launch_bounds__(128, 1) void ctc_kernel(
    const int* __restrict__ labels, const int* __restrict__ act_lens,
    const int* __restrict__ label_lens, const int* __restrict__ offsets,
    const float* __restrict__ lse_rows, const unsigned short* __restrict__ packedU,
    const float* __restrict__ blankU, float* __restrict__ out)
{
    __shared__ uint4 ubuf[2][2][C * 32];   // [wave][buf][chunk image] 8KB each = 32 KB
    __shared__ float bbuf[2][2][C];
    __shared__ float sbr[S];
    __shared__ float s_accb;

    const int b    = blockIdx.x;
    const int wave = threadIdx.x >> 6;
    const int lane = threadIdx.x & 63;
    const int lab_len = label_lens[b];
    const int a_len   = act_lens[b];
    const int th      = (a_len - 1) >> 1;
    const int off     = offsets[b];
    const size_t rowbase = (size_t)b * T;

    int li0 = 4 * lane;
    int eprev = (li0 - 1 >= 0 && li0 - 1 < lab_len) ? labels[min(off + li0 - 1, B * L - 1)] : 0;
    int enext = (li0 + 4 < lab_len) ? labels[min(off + li0 + 4, B * L - 1)] : 0;
    int e0 = (li0 + 0 < lab_len) ? labels[min(off + li0 + 0, B * L - 1)] : 0;
    int e1 = (li0 + 1 < lab_len) ? labels[min(off + li0 + 1, B * L - 1)] : 0;
    int e2 = (li0 + 2 < lab_len) ? labels[min(off + li0 + 2, B * L - 1)] : 0;
    int e3 = (li0 + 3 < lab_len) ? labels[min(off + li0 + 3, B * L - 1)] : 0;

    const float aF0 = (8 * lane + 1 >= 2 && e0 != 0 && e0 != eprev) ? 1.f : 0.f;
    const float aF1 = (e1 != 0 && e1 != e0) ? 1.f : 0.f;
    const float aF2 = (e2 != 0 && e2 != e1) ? 1.f : 0.f;
    const float aF3 = (e3 != 0 && e3 != e2) ? 1.f : 0.f;
    const float aB0 = aF1, aB1 = aF2, aB2 = aF3;
    const float aB3 = (enext != 0 && enext != e3) ? 1.f : 0.f;

    float A0 = 0.f, A1 = 0.f, A2 = 0.f, A3 = 0.f, A4 = 0.f,
          A5 = 0.f, A6 = 0.f, A7 = 0.f, A8 = 0.f;
    float acc = 0.f, sls = 0.f;
    uint4 G0, G1, G2, G3, G4, G5, G6, G7;
    float BL = 0.f;

#define LOADCHUNK(TLO) do {                                                   \
        const uint4* gp_ = (const uint4*)(packedU + (rowbase + (TLO)) * 256); \
        G0 = gp_[lane];       G1 = gp_[lane + 64];                            \
        G2 = gp_[lane + 128]; G3 = gp_[lane + 192];                           \
        G4 = gp_[lane + 256]; G5 = gp_[lane + 320];                           \
        G6 = gp_[lane + 384]; G7 = gp_[lane + 448];                           \
        if (lane < C) BL = blankU[rowbase + (TLO) + lane];                    \
    } while (0)

#define WRITEBUF(BI) do {                                                     \
        uint4* wp_ = ubuf[wave][BI];                                          \
        wp_[lane] = G0;       wp_[lane + 64] = G1;                            \
        wp_[lane + 128] = G2; wp_[lane + 192] = G3;                           \
        wp_[lane + 256] = G4; wp_[lane + 320] = G5;                           \
        wp_[lane + 384] = G6; wp_[lane + 448] = G7;                           \
        if (lane < C) bbuf[wave][BI][lane] = BL;                              \
    } while (0)

#define RESCALE() do {                                                        \
        float m_ = fmaxf(A8, A0); m_ = fmaxf(m_, A1); m_ = fmaxf(m_, A2);     \
        m_ = fmaxf(m_, A3); m_ = fmaxf(m_, A4); m_ = fmaxf(m_, A5);           \
        m_ = fmaxf(m_, A6); m_ = fmaxf(m_, A7);                               \
        _Pragma("unroll")                                                     \
        for (int o_ = 32; o_; o_ >>= 1) m_ = fmaxf(m_, __shfl_xor(m_, o_, 64)); \
        m_ = fmaxf(m_, 1e-30f);                                               \
        float inv_ = __builtin_amdgcn_rcpf(m_);                               \
        acc += __logf(m_);                                                    \
        A0 *= inv_; A1 *= inv_; A2 *= inv_; A3 *= inv_; A4 *= inv_;           \
        A5 *= inv_; A6 *= inv_; A7 *= inv_; A8 *= inv_;                       \
    } while (0)

#define STEPF(BI, ROW) do {                                                   \
        uint2 hv_ = ((const uint2*)ubuf[wave][BI])[(ROW) * 64 + lane];        \
        float ub_ = bbuf[wave][BI][ROW];                                      \
        float u0_ = __uint_as_float(hv_.x << 16);                             \
        float u1_ = __uint_as_float(hv_.x & 0xffff0000u);                     \
        float u2_ = __uint_as_float(hv_.y << 16);                             \
        float u3_ = __uint_as_float(hv_.y & 0xffff0000u);                     \
        float pA7_ = __shfl_up(A7, 1, 64);                                    \
        if (lane == 0) pA7_ = 0.f;                                            \
        A8 = ub_ * (A8 + A7);                                                 \
        A7 = u3_ * fmaf(aF3, A5, A7 + A6);                                    \
        A6 = ub_ * (A6 + A5);                                                 \
        A5 = u2_ * fmaf(aF2, A3, A5 + A4);                                    \
        A4 = ub_ * (A4 + A3);                                                 \
        A3 = u1_ * fmaf(aF1, A1, A3 + A2);                                    \
        A2 = ub_ * (A2 + A1);                                                 \
        A1 = u0_ * fmaf(aF0, pA7_, A1 + A0);                                  \
        A0 = ub_ * (A0 + pA7_);                                               \
    } while (0)

#define STEPB(BI, ROW) do {                                                   \
        uint2 hv_ = ((const uint2*)ubuf[wave][BI])[(ROW) * 64 + lane];        \
        float ub_ = bbuf[wave][BI][ROW];                                      \
        float u0_ = __uint_as_float(hv_.x << 16);                             \
        float u1_ = __uint_as_float(hv_.x & 0xffff0000u);                     \
        float u2_ = __uint_as_float(hv_.y << 16);                             \
        float u3_ = __uint_as_float(hv_.y & 0xffff0000u);                     \
        float nB0_ = __shfl_down(A0, 1, 64);                                  \
        float nB1_ = __shfl_down(A1, 1, 64);                                  \
        if (lane == 63) { nB0_ = A8; nB1_ = 0.f; }                            \
        A8 = ub_ * A8;                                                        \
        A0 = ub_ * (A0 + A1);                                                 \
        A1 = u0_ * fmaf(aB0, A3, A1 + A2);                                    \
        A2 = ub_ * (A2 + A3);                                                 \
        A3 = u1_ * fmaf(aB1, A5, A3 + A4);                                    \
        A4 = ub_ * (A4 + A5);                                                 \
        A5 = u2_ * fmaf(aB2, A7, A5 + A6);                                    \
        A6 = ub_ * (A6 + A7);                                                 \
        A7 = u3_ * fmaf(aB3, nB1_, A7 + nB0_);                                \
    } while (0)

    if (wave == 0) {
        for (int t = lane; t < a_len; t += 64) sls += lse_rows[rowbase + t];
#pragma unroll
        for (int o = 32; o; o >>= 1) sls += __shfl_xor(sls, o, 64);

        if (lane == 0) {
            A0 = blankU[rowbase];
            A1 = __uint_as_float(((unsigned)packedU[rowbase * 256]) << 16);
        }

        const int nst = th;                      // steps t = 1..th
        if (nst > 0) {
            const int nc = (nst + C - 1) / C;
            LOADCHUNK(1);
            WRITEBUF(0);
            LOADCHUNK(1 + C * min(1, nc - 1));
            for (int k = 0; k < nc; ++k) {
                const int bi  = k & 1;
                const int tlo = 1 + C * k;
#pragma unroll
                for (int i = 0; i < C; ++i) {
                    if (tlo + i <= th) STEPF(bi, i);
                    if (i == 7 || i == 15) RESCALE();
                }
                WRITEBUF((k + 1) & 1);           // G = chunk k+1 (loaded at k-1)
                LOADCHUNK(1 + C * min(k + 2, nc - 1));
            }
        }
    } else {
        const int send = 2 * lab_len;
        {
            size_t rl = rowbase + (a_len - 1);
            float ubl = blankU[rl];
            float ue  = (lab_len > 0)
                      ? __uint_as_float(((unsigned)packedU[rl * 256 + (lab_len - 1)]) << 16)
                      : 0.f;
            int s0 = 8 * lane;
            A0 = (s0 + 0 == send) ? ubl : ((s0 + 0 == send - 1) ? ue : 0.f);
            A1 = (s0 + 1 == send) ? ubl : ((s0 + 1 == send - 1) ? ue : 0.f);
            A2 = (s0 + 2 == send) ? ubl : ((s0 + 2 == send - 1) ? ue : 0.f);
            A3 = (s0 + 3 == send) ? ubl : ((s0 + 3 == send - 1) ? ue : 0.f);
            A4 = (s0 + 4 == send) ? ubl : ((s0 + 4 == send - 1) ? ue : 0.f);
            A5 = (s0 + 5 == send) ? ubl : ((s0 + 5 == send - 1) ? ue : 0.f);
            A6 = (s0 + 6 == send) ? ubl : ((s0 + 6 == send - 1) ? ue : 0.f);
            A7 = (s0 + 7 == send) ? ubl : ((s0 + 7 == send - 1) ? ue : 0.f);
            A8 = (lane == 63 && send == 512) ? ubl : 0.f;
        }

        const int nst = a_len - 2 - th;          // steps t = a_len-2 .. th+1
        if (nst > 0) {
            const int nc = (nst + C - 1) / C;
#define BTLO(K) max(a_len - 2 - C * (K) - (C - 1), 0)
            LOADCHUNK(BTLO(0));
            WRITEBUF(0);
            LOADCHUNK(BTLO(min(1, nc - 1)));
            for (int k = 0; k < nc; ++k) {
                const int bi   = k & 1;
                const int thi  = a_len - 2 - C * k;
                const int tloc = max(thi - (C - 1), 0);
#pragma unroll
                for (int i = 0; i < C; ++i) {
                    int tt = thi - i;
                    if (tt >= th + 1) STEPB(bi, tt - tloc);
                    if (i == 7 || i == 15) RESCALE();
                }
                WRITEBUF((k + 1) & 1);
                LOADCHUNK(BTLO(min(k + 2, nc - 1)));
            }
#undef BTLO
        }

        {   // bracket W(s) = B(s) + B(s+1) + allowB*B(s+2), B = beta_{th+1}
            float nB0 = __shfl_down(A0, 1, 64);
            float nB1 = __shfl_down(A1, 1, 64);
            if (lane == 63) { nB0 = A8; nB1 = 0.f; }
            float w0 = A0 + A1;
            float w1 = fmaf(aB0, A3, A1 + A2);
            float w2 = A2 + A3;
            float w3 = fmaf(aB1, A5, A3 + A4);
            float w4 = A4 + A5;
            float w5 = fmaf(aB2, A7, A5 + A6);
            float w6 = A6 + A7;
            float w7 = fmaf(aB3, nB1, A7 + nB0);
            int s0 = 8 * lane;
            sbr[s0 + 0] = w0; sbr[s0 + 1] = w1; sbr[s0 + 2] = w2; sbr[s0 + 3] = w3;
            sbr[s0 + 4] = w4; sbr[s0 + 5] = w5; sbr[s0 + 6] = w6; sbr[s0 + 7] = w7;
            if (lane == 63) sbr[512] = A8;
            if (lane == 0)  s_accb = acc;
        }
    }
    __syncthreads();
    if (wave == 0) {
        // LOG-space junction (linear dot of the two independently-rescaled
        // sides underflows fp32 — R3's inf)
        int s0 = 8 * lane;
        float p0 = __logf(fmaxf(A0, 1e-37f)) + __logf(fmaxf(sbr[s0 + 0], 1e-37f));
        float p1 = __logf(fmaxf(A1, 1e-37f)) + __logf(fmaxf(sbr[s0 + 1], 1e-37f));
        float p2 = __logf(fmaxf(A2, 1e-37f)) + __logf(fmaxf(sbr[s0 + 2], 1e-37f));
        float p3 = __logf(fmaxf(A3, 1e-37f)) + __logf(fmaxf(sbr[s0 + 3], 1e-37f));
        float p4 = __logf(fmaxf(A4, 1e-37f)) + __logf(fmaxf(sbr[s0 + 4], 1e-37f));
        float p5 = __logf(fmaxf(A5, 1e-37f)) + __logf(fmaxf(sbr[s0 + 5], 1e-37f));
        float p6 = __logf(fmaxf(A6, 1e-37f)) + __logf(fmaxf(sbr[s0 + 6], 1e-37f));
        float p7 = __logf(fmaxf(A7, 1e-37f)) + __logf(fmaxf(sbr[s0 + 7], 1e-37f));
        float p8 = -3.0e38f;
        if (lane == 63) p8 = __logf(fmaxf(A8, 1e-37f)) + __logf(fmaxf(sbr[512], 1e-37f));
        float pmax = fmaxf(fmaxf(fmaxf(p0, p1), fmaxf(p2, p3)),
                           fmaxf(fmaxf(p4, p5), fmaxf(p6, p7)));
        pmax = fmaxf(pmax, p8);
#pragma unroll
        for (int o = 32; o; o >>= 1) pmax = fmaxf(pmax, __shfl_xor(pmax, o, 64));
        float dot = __expf(p0 - pmax) + __expf(p1 - pmax) + __expf(p2 - pmax)
                  + __expf(p3 - pmax) + __expf(p4 - pmax) + __expf(p5 - pmax)
                  + __expf(p6 - pmax) + __expf(p7 - pmax);
        if (lane == 63) dot += __expf(p8 - pmax);
#pragma unroll
        for (int o = 32; o; o >>= 1) dot += __shfl_xor(dot, o, 64);
        if (lane == 0) {
            float loss = sls - acc - s_accb - (pmax + __logf(dot));
            atomicAdd(out, loss);
        }
    }
#undef LOADCHUNK
#undef WRITEBUF
#undef RESCALE
#undef STEPF
#undef STEPB
}

extern "C" void kernel_launch(void* const* d_in, const int* in_sizes, int n_in,
                              void* d_out, int out_size, void* d_ws, size_t ws_size,
                              hipStream_t stream) {
    const float* acts       = (const float*)d_in[0];
    const int*   labels     = (const int*)d_in[1];
    const int*   act_lens   = (const int*)d_in[2];
    const int*   label_lens = (const int*)d_in[3];
    float*       out        = (float*)d_out;

    float*          lse_rows = (float*)d_ws;
    float*          blankU   = (float*)((char*)d_ws + (size_t)T * B * 4);
    int*            offsets  = (int*)  ((char*)d_ws + (size_t)2 * T * B * 4);
    unsigned short* packedU  = (unsigned short*)((char*)d_ws + (1u << 20));

    hipMemsetAsync(d_out, 0, sizeof(float), stream);

    offsets_kernel<<<1, 64, 0, stream>>>(label_lens, offsets);
    setup_kernel<<<T * B / 8, 256, 0, stream>>>(
        acts, labels, label_lens, offsets, lse_rows, packedU, blankU);
    ctc_kernel<<<B, 128, 0, stream>>>(
        labels, act_lens, label_lens, offsets, lse_rows, packedU, blankU, out);
}